// Round 8
// baseline (108.798 us; speedup 1.0000x reference)
//
#include <hip/hip_runtime.h>
#include <stdint.h>

#define S 2048
#define DHEAD 64
#define CDIM 256
#define NBATCH 8
#define NMT 16  // S/128 m-tiles

typedef __attribute__((ext_vector_type(4))) float f32x4;
typedef __attribute__((ext_vector_type(8))) short s16x8;
typedef __attribute__((ext_vector_type(8))) _Float16 f16x8;
typedef __attribute__((ext_vector_type(4))) unsigned short u16x4;

static __device__ __forceinline__ unsigned short f2bf(float f) {
    unsigned int u = __builtin_bit_cast(unsigned int, f);
    unsigned int r = (u + 0x7FFFu + ((u >> 16) & 1u)) >> 16;  // RNE
    return (unsigned short)r;
}
static __device__ __forceinline__ unsigned short f2h(float f) {
    _Float16 h = (_Float16)f;
    return __builtin_bit_cast(unsigned short, h);
}
static __device__ __forceinline__ float bf2f(unsigned short u) {
    return __builtin_bit_cast(float, (unsigned int)u << 16);
}

// ---------------- kernel 0: a (fp32) -> a16 (bf16) ----------------
__global__ __launch_bounds__(256) void cvt_a_kernel(const float* __restrict__ a,
                                                    unsigned short* __restrict__ a16,
                                                    int n4) {
    int i = blockIdx.x * 256 + threadIdx.x;
    int stride = gridDim.x * 256;
    for (; i < n4; i += stride) {
        f32x4 v = ((const f32x4*)a)[i];
        u16x4 o;
        o.x = f2bf(v.x); o.y = f2bf(v.y); o.z = f2bf(v.z); o.w = f2bf(v.w);
        ((u16x4*)a16)[i] = o;
    }
}

// ---------------- kernel 1: E = exp(b @ c^T) via f16 MFMA (R2-verified) ----
// 1-D grid; when nb==8, batch==XCD so E lines land in that XCD's L2.
__global__ __launch_bounds__(256) void scores_kernel(
    const float* __restrict__ Bq, const float* __restrict__ Ck,
    unsigned short* __restrict__ E, float* __restrict__ Lp, int b0, int nb)
{
    const int bid = blockIdx.x;
    int lb, idx;
    if (nb == 8) { lb = bid & 7; idx = bid >> 3; }
    else { lb = bid / (NMT * 16); idx = bid - lb * (NMT * 16); }
    const int gb = b0 + lb;
    const int mt = idx & 15;
    const int m0 = mt * 128;
    const int n0 = (idx >> 4) * 128;
    const float* __restrict__ bp = Bq + (size_t)gb * S * DHEAD;
    const float* __restrict__ cp = Ck + (size_t)gb * S * DHEAD;
    unsigned short* __restrict__ Ep = E + (size_t)lb * S * S;

    extern __shared__ char smem[];
    unsigned short* cs = (unsigned short*)smem;        // [128][72] f16 (m rows)
    unsigned short* bs = cs + 128 * 72;                // [128][72] f16 (n rows)
    unsigned short* es = (unsigned short*)smem;        // [128][136] bf16, ALIASES cs/bs
    float* Lsh = (float*)(smem + 2 * 128 * 72 * 2);    // [2][128]

    const int tid = threadIdx.x;
    const int lane = tid & 63;
    const int wid = tid >> 6;
    const int wr = wid >> 1, wc = wid & 1;
    const int q = lane >> 4, r15 = lane & 15;

    #pragma unroll
    for (int t = 0; t < 8; ++t) {
        int ch = tid + 256 * t;
        int row = ch >> 4, c4 = ch & 15;
        f32x4 cv = *(const f32x4*)&cp[(size_t)(m0 + row) * DHEAD + c4 * 4];
        f32x4 bv = *(const f32x4*)&bp[(size_t)(n0 + row) * DHEAD + c4 * 4];
        u16x4 co, bo;
        co.x = f2h(cv.x); co.y = f2h(cv.y); co.z = f2h(cv.z); co.w = f2h(cv.w);
        bo.x = f2h(bv.x); bo.y = f2h(bv.y); bo.z = f2h(bv.z); bo.w = f2h(bv.w);
        *(u16x4*)&cs[row * 72 + c4 * 4] = co;
        *(u16x4*)&bs[row * 72 + c4 * 4] = bo;
    }
    __syncthreads();

    f32x4 acc[4][4] = {};
    #pragma unroll
    for (int kk = 0; kk < 2; ++kk) {
        f16x8 af[4], bf[4];
        #pragma unroll
        for (int i = 0; i < 4; ++i)
            af[i] = *(const f16x8*)&cs[(wr * 64 + i * 16 + r15) * 72 + kk * 32 + q * 8];
        #pragma unroll
        for (int j = 0; j < 4; ++j)
            bf[j] = *(const f16x8*)&bs[(wc * 64 + j * 16 + r15) * 72 + kk * 32 + q * 8];
        #pragma unroll
        for (int i = 0; i < 4; ++i)
            #pragma unroll
            for (int j = 0; j < 4; ++j)
                acc[i][j] = __builtin_amdgcn_mfma_f32_16x16x32_f16(af[i], bf[j], acc[i][j], 0, 0, 0);
    }

    u16x4 pk[4][4];
    float sj[4] = {0.f, 0.f, 0.f, 0.f};
    #pragma unroll
    for (int i = 0; i < 4; ++i) {
        #pragma unroll
        for (int j = 0; j < 4; ++j) {
            float e0 = __expf(acc[i][j][0]);
            float e1 = __expf(acc[i][j][1]);
            float e2 = __expf(acc[i][j][2]);
            float e3 = __expf(acc[i][j][3]);
            pk[i][j].x = f2bf(e0); pk[i][j].y = f2bf(e1);
            pk[i][j].z = f2bf(e2); pk[i][j].w = f2bf(e3);
            sj[j] += (e0 + e1) + (e2 + e3);
        }
    }
    #pragma unroll
    for (int j = 0; j < 4; ++j) {
        sj[j] += __shfl_xor(sj[j], 16);
        sj[j] += __shfl_xor(sj[j], 32);
    }

    __syncthreads();

    #pragma unroll
    for (int i = 0; i < 4; ++i)
        #pragma unroll
        for (int j = 0; j < 4; ++j) {
            int nl = wc * 64 + j * 16 + r15;
            int ml = wr * 64 + i * 16 + q * 4;
            *(u16x4*)&es[nl * 136 + ml] = pk[i][j];
        }
    if (q == 0) {
        #pragma unroll
        for (int j = 0; j < 4; ++j)
            Lsh[wr * 128 + wc * 64 + j * 16 + r15] = sj[j];
    }
    __syncthreads();

    if (tid < 128)
        Lp[(size_t)lb * NMT * S + (size_t)mt * S + n0 + tid] = Lsh[tid] + Lsh[128 + tid];

    #pragma unroll
    for (int t = 0; t < 8; ++t) {
        int ch = tid + 256 * t;
        int row = ch >> 4, off = ch & 15;
        f32x4 v = *(const f32x4*)&es[row * 136 + off * 8];
        *(f32x4*)&Ep[(size_t)(n0 + row) * S + m0 + off * 8] = v;
    }
}

// ---------------- kernel 2: out = (a16 @ E^T) / L + a16 ----------------
// 128c x 64n tile, BK=64, 4 waves (2 wr x 2 wc).
// Pipe split: A (a16) fragments read DIRECTLY from global/L2 (1 MB/batch,
// L2-resident on its XCD; per-lane pattern validated in R3/R4); only E is
// staged in LDS (double-buffered, pad 72, T14 reg-prefetch). This cuts LDS
// traffic ~3x vs R7 (was LDS-BW-bound at ~85 B/cyc/CU) and runs the LDS and
// L2 pipes concurrently.
__global__ __launch_bounds__(256, 4) void gemm_kernel(
    const unsigned short* __restrict__ a16, const unsigned short* __restrict__ E,
    const float* __restrict__ Lp, float* __restrict__ out, int b0, int nb)
{
    const int bid = blockIdx.x;
    int lb, idx;
    if (nb == 8) { lb = bid & 7; idx = bid >> 3; }
    else { lb = bid / 64; idx = bid - lb * 64; }
    const int gb = b0 + lb;
    const int nt = idx >> 1, ct = idx & 1;   // ct-pairs adjacent -> share E rows in L2
    const int n0 = nt * 64, c0 = ct * 128;

    const unsigned short* __restrict__ Ap = a16 + (size_t)gb * CDIM * S;
    const unsigned short* __restrict__ Bp = E + (size_t)lb * S * S;
    float* __restrict__ op = out + (size_t)gb * CDIM * S;

    __shared__ unsigned short Bs[2][64 * 72];  // E rows padded to 72 shorts

    const int tid = threadIdx.x;
    const int lane = tid & 63;
    const int w = tid >> 6;
    const int wr = w >> 1, wc = w & 1;
    const int q = lane >> 4, r15 = lane & 15;

    // B staging decode (16 B chunks; 8 chunks per 64-short row; 2/thread)
    const int brow[2] = { (tid) >> 3, (tid + 256) >> 3 };
    const int boff[2] = { (tid) & 7, (tid + 256) & 7 };

    // A fragment row bases (global)
    size_t arow_base[4];
    #pragma unroll
    for (int i = 0; i < 4; ++i)
        arow_base[i] = (size_t)(c0 + wr * 64 + i * 16 + r15) * S + q * 8;

    f32x4 acc[4][2] = {};
    f32x4 bvr[2];

    // prologue: load E K-tile 0, write buf0
    #pragma unroll
    for (int t = 0; t < 2; ++t)
        bvr[t] = *(const f32x4*)&Bp[(size_t)(n0 + brow[t]) * S + boff[t] * 8];
    #pragma unroll
    for (int t = 0; t < 2; ++t)
        *(f32x4*)&Bs[0][brow[t] * 72 + boff[t] * 8] = bvr[t];
    __syncthreads();

    #pragma unroll 2
    for (int kt = 0; kt < S / 64; ++kt) {
        const int cur = kt & 1;
        const int k0 = kt * 64;

        // A-fragments for this step: 8 global loads (L2-hot), needed first
        s16x8 af[2][4];
        #pragma unroll
        for (int kk = 0; kk < 2; ++kk)
            #pragma unroll
            for (int i = 0; i < 4; ++i)
                af[kk][i] = *(const s16x8*)&Ap[arow_base[i] + k0 + kk * 32];

        // T14: next E tile loads; latency hides under MFMA below
        if (kt < S / 64 - 1) {
            #pragma unroll
            for (int t = 0; t < 2; ++t)
                bvr[t] = *(const f32x4*)&Bp[(size_t)(n0 + brow[t]) * S + k0 + 64 + boff[t] * 8];
        }

        const unsigned short* Br = Bs[cur];
        #pragma unroll
        for (int kk = 0; kk < 2; ++kk) {
            s16x8 bf[2];
            #pragma unroll
            for (int j = 0; j < 2; ++j)
                bf[j] = *(const s16x8*)&Br[(wc * 32 + j * 16 + r15) * 72 + kk * 32 + q * 8];
            #pragma unroll
            for (int i = 0; i < 4; ++i)
                #pragma unroll
                for (int j = 0; j < 2; ++j)
                    acc[i][j] = __builtin_amdgcn_mfma_f32_16x16x32_bf16(af[kk][i], bf[j], acc[i][j], 0, 0, 0);
        }

        // write next E tile into the idle buffer
        if (kt < S / 64 - 1) {
            unsigned short* Bw = Bs[cur ^ 1];
            #pragma unroll
            for (int t = 0; t < 2; ++t)
                *(f32x4*)&Bw[brow[t] * 72 + boff[t] * 8] = bvr[t];
        }
        __syncthreads();  // buf[cur^1] ready; all reads of buf[cur] retired
    }

    // epilogue: out = acc / L[n] + a (residual from L2-hot a16)
    float rcpL[2];
    #pragma unroll
    for (int j = 0; j < 2; ++j) {
        int n = n0 + wc * 32 + j * 16 + r15;
        float s = 0.f;
        #pragma unroll
        for (int mt = 0; mt < NMT; ++mt)
            s += Lp[(size_t)lb * NMT * S + (size_t)mt * S + n];
        rcpL[j] = 1.0f / s;
    }
    #pragma unroll
    for (int i = 0; i < 4; ++i) {
        #pragma unroll
        for (int rr = 0; rr < 4; ++rr) {
            int cc = c0 + wr * 64 + i * 16 + q * 4 + rr;
            size_t base = (size_t)cc * S;
            #pragma unroll
            for (int j = 0; j < 2; ++j) {
                int n = n0 + wc * 32 + j * 16 + r15;
                op[base + n] = acc[i][j][rr] * rcpL[j] + bf2f(Ap[base + n]);
            }
        }
    }
}

// ---------------- launch ----------------
extern "C" void kernel_launch(void* const* d_in, const int* in_sizes, int n_in,
                              void* d_out, int out_size, void* d_ws, size_t ws_size,
                              hipStream_t stream) {
    const float* a = (const float*)d_in[0];
    const float* b = (const float*)d_in[1];
    const float* c = (const float*)d_in[2];
    float* out = (float*)d_out;

    const size_t a16_bytes = (size_t)NBATCH * CDIM * S * 2;              // 8 MB
    const size_t perb = (size_t)S * S * 2 + (size_t)NMT * S * 4;         // ~8.5 MB per batch
    int G = 1;
    if (ws_size > a16_bytes + perb) {
        size_t g = (ws_size - a16_bytes) / perb;
        G = (g >= NBATCH) ? NBATCH : (int)g;
        if (G < 1) G = 1;
    }
    unsigned short* a16 = (unsigned short*)d_ws;
    unsigned short* E = (unsigned short*)((char*)d_ws + a16_bytes);
    float* Lp = (float*)((char*)d_ws + a16_bytes + (size_t)G * S * S * 2);

    cvt_a_kernel<<<1024, 256, 0, stream>>>(a, a16, NBATCH * CDIM * S / 4);

    const size_t lds1 = 2 * 128 * 72 * 2 + 2 * 128 * 4;   // 37888 B
    for (int b0 = 0; b0 < NBATCH; b0 += G) {
        int nb = (NBATCH - b0 < G) ? (NBATCH - b0) : G;
        scores_kernel<<<NMT * 16 * nb, 256, lds1, stream>>>(b, c, E, Lp, b0, nb);
        gemm_kernel<<<64 * nb, 256, 0, stream>>>(a16, E, Lp, out, b0, nb);
    }
}

// Round 9
// 61.541 us; speedup vs baseline: 1.7679x; 1.7679x over previous
//
#include <hip/hip_runtime.h>
#include <stdint.h>

#define S 2048
#define DHEAD 64
#define CDIM 256
#define NBATCH 8
#define NMT 16  // S/128 m-tiles

typedef __attribute__((ext_vector_type(4))) float f32x4;
typedef __attribute__((ext_vector_type(8))) short s16x8;
typedef __attribute__((ext_vector_type(8))) _Float16 f16x8;
typedef __attribute__((ext_vector_type(4))) unsigned short u16x4;

static __device__ __forceinline__ unsigned short f2bf(float f) {
    unsigned int u = __builtin_bit_cast(unsigned int, f);
    unsigned int r = (u + 0x7FFFu + ((u >> 16) & 1u)) >> 16;  // RNE
    return (unsigned short)r;
}
static __device__ __forceinline__ unsigned short f2h(float f) {
    _Float16 h = (_Float16)f;
    return __builtin_bit_cast(unsigned short, h);
}
static __device__ __forceinline__ float bf2f(unsigned short u) {
    return __builtin_bit_cast(float, (unsigned int)u << 16);
}

// async global->LDS, 16B per lane; LDS dest = wave-uniform base + lane*16
#define GLOAD16(g, l)                                                              \
    __builtin_amdgcn_global_load_lds(                                              \
        (const __attribute__((address_space(1))) void*)(g),                        \
        (__attribute__((address_space(3))) void*)(l), 16, 0, 0)

// ---- kernel 0: a->bf16, b->f16, c->f16 -------------------------------------
__global__ __launch_bounds__(256) void cvt_kernel(
    const float* __restrict__ a, const float* __restrict__ b, const float* __restrict__ c,
    unsigned short* __restrict__ a16, unsigned short* __restrict__ b16,
    unsigned short* __restrict__ c16)
{
    const int na4 = NBATCH * CDIM * S / 4;
    const int nbc4 = NBATCH * S * DHEAD / 4;
    int i0 = blockIdx.x * 256 + threadIdx.x;
    int stride = gridDim.x * 256;
    for (int i = i0; i < na4; i += stride) {
        f32x4 v = ((const f32x4*)a)[i];
        u16x4 o; o.x = f2bf(v.x); o.y = f2bf(v.y); o.z = f2bf(v.z); o.w = f2bf(v.w);
        ((u16x4*)a16)[i] = o;
    }
    for (int i = i0; i < nbc4; i += stride) {
        f32x4 v = ((const f32x4*)b)[i];
        u16x4 o; o.x = f2h(v.x); o.y = f2h(v.y); o.z = f2h(v.z); o.w = f2h(v.w);
        ((u16x4*)b16)[i] = o;
        f32x4 u = ((const f32x4*)c)[i];
        u16x4 p; p.x = f2h(u.x); p.y = f2h(u.y); p.z = f2h(u.z); p.w = f2h(u.w);
        ((u16x4*)c16)[i] = p;
    }
}

// ---- kernel 1: E = exp(b @ c^T) via f16 MFMA (R2-verified layout) ----------
// Staging via global_load_lds with both-sides XOR swizzle: LDS rows = 64 f16
// (128 B), linear dest; global chunk pre-swizzled off^=(row&7); reads apply
// the same XOR. 1-D grid; nb==8 -> batch==XCD.
__global__ __launch_bounds__(256) void scores_kernel(
    const unsigned short* __restrict__ B16, const unsigned short* __restrict__ C16,
    unsigned short* __restrict__ E, float* __restrict__ Lp, int b0, int nb)
{
    const int bid = blockIdx.x;
    int lb, idx;
    if (nb == 8) { lb = bid & 7; idx = bid >> 3; }
    else { lb = bid / (NMT * 16); idx = bid - lb * (NMT * 16); }
    const int gb = b0 + lb;
    const int mt = idx & 15;
    const int m0 = mt * 128;
    const int n0 = (idx >> 4) * 128;
    const unsigned short* __restrict__ bp = B16 + (size_t)gb * S * DHEAD;
    const unsigned short* __restrict__ cp = C16 + (size_t)gb * S * DHEAD;
    unsigned short* __restrict__ Ep = E + (size_t)lb * S * S;

    extern __shared__ char smem[];
    unsigned short* cs = (unsigned short*)smem;          // [128][64] f16 swz
    unsigned short* bs = cs + 128 * 64;                  // [128][64] f16 swz
    unsigned short* es = (unsigned short*)smem;          // [128][136] bf16, alias
    float* Lsh = (float*)(smem + 34816);                 // [2][128]

    const int tid = threadIdx.x;
    const int lane = tid & 63;
    const int w = tid >> 6;
    const int wr = w >> 1, wc = w & 1;
    const int q = lane >> 4, r15 = lane & 15;

    // stage c (m rows) + b (n rows): 16 wave-rounds each of 64 chunks
    #pragma unroll
    for (int t = 0; t < 4; ++t) {
        int r = w + 4 * t;
        int ch = r * 64 + lane;
        int row = ch >> 3;
        int off = ((ch & 7) ^ (row & 7)) * 8;  // shorts
        GLOAD16(cp + (size_t)(m0 + row) * DHEAD + off, &cs[r * 512]);
        GLOAD16(bp + (size_t)(n0 + row) * DHEAD + off, &bs[r * 512]);
    }
    __syncthreads();  // vmcnt(0) drain -> DMA complete

    f32x4 acc[4][4] = {};
    #pragma unroll
    for (int kk = 0; kk < 2; ++kk) {
        const int sz = ((kk * 4 + q) ^ (r15 & 7)) * 8;
        f16x8 af[4], bf[4];
        #pragma unroll
        for (int i = 0; i < 4; ++i)
            af[i] = *(const f16x8*)&cs[(wr * 64 + i * 16 + r15) * 64 + sz];
        #pragma unroll
        for (int j = 0; j < 4; ++j)
            bf[j] = *(const f16x8*)&bs[(wc * 64 + j * 16 + r15) * 64 + sz];
        #pragma unroll
        for (int i = 0; i < 4; ++i)
            #pragma unroll
            for (int j = 0; j < 4; ++j)
                acc[i][j] = __builtin_amdgcn_mfma_f32_16x16x32_f16(af[i], bf[j], acc[i][j], 0, 0, 0);
    }

    u16x4 pk[4][4];
    float sj[4] = {0.f, 0.f, 0.f, 0.f};
    #pragma unroll
    for (int i = 0; i < 4; ++i) {
        #pragma unroll
        for (int j = 0; j < 4; ++j) {
            float e0 = __expf(acc[i][j][0]);
            float e1 = __expf(acc[i][j][1]);
            float e2 = __expf(acc[i][j][2]);
            float e3 = __expf(acc[i][j][3]);
            pk[i][j].x = f2bf(e0); pk[i][j].y = f2bf(e1);
            pk[i][j].z = f2bf(e2); pk[i][j].w = f2bf(e3);
            sj[j] += (e0 + e1) + (e2 + e3);
        }
    }
    #pragma unroll
    for (int j = 0; j < 4; ++j) {
        sj[j] += __shfl_xor(sj[j], 16);
        sj[j] += __shfl_xor(sj[j], 32);
    }

    __syncthreads();  // all fragment reads retired -> es may overwrite cs/bs

    #pragma unroll
    for (int i = 0; i < 4; ++i)
        #pragma unroll
        for (int j = 0; j < 4; ++j) {
            int nl = wc * 64 + j * 16 + r15;
            int ml = wr * 64 + i * 16 + q * 4;
            *(u16x4*)&es[nl * 136 + ml] = pk[i][j];
        }
    if (q == 0) {
        #pragma unroll
        for (int j = 0; j < 4; ++j)
            Lsh[wr * 128 + wc * 64 + j * 16 + r15] = sj[j];
    }
    __syncthreads();

    if (tid < 128)
        Lp[(size_t)lb * NMT * S + (size_t)mt * S + n0 + tid] = Lsh[tid] + Lsh[128 + tid];

    #pragma unroll
    for (int t = 0; t < 8; ++t) {
        int ch = tid + 256 * t;
        int row = ch >> 4, off = ch & 15;
        f32x4 v = *(const f32x4*)&es[row * 136 + off * 8];
        *(f32x4*)&Ep[(size_t)(n0 + row) * S + m0 + off * 8] = v;
    }
}

// ---- kernel 2: out = (a16 @ E^T) / L + a16 ---------------------------------
// 128c x 64n tile, BK=64, 4 waves (2x2). Staging via global_load_lds
// (double-buffered, one barrier per K-step); both-sides XOR swizzle as above.
__global__ __launch_bounds__(256, 2) void gemm_kernel(
    const unsigned short* __restrict__ a16, const unsigned short* __restrict__ E,
    const float* __restrict__ Lp, float* __restrict__ out, int b0, int nb)
{
    const int bid = blockIdx.x;
    int lb, idx;
    if (nb == 8) { lb = bid & 7; idx = bid >> 3; }
    else { lb = bid / 64; idx = bid - lb * 64; }
    const int gb = b0 + lb;
    const int nt = idx >> 1, ct = idx & 1;   // ct-pairs adjacent -> share E rows in L2
    const int n0 = nt * 64, c0 = ct * 128;

    const unsigned short* __restrict__ Ap = a16 + (size_t)gb * CDIM * S;
    const unsigned short* __restrict__ Bp = E + (size_t)lb * S * S;
    float* __restrict__ op = out + (size_t)gb * CDIM * S;

    __shared__ unsigned short As[2][128 * 64];  // 16 KB per buf, swizzled
    __shared__ unsigned short Bs[2][64 * 64];   // 8 KB per buf

    const int tid = threadIdx.x;
    const int lane = tid & 63;
    const int w = tid >> 6;
    const int wr = w >> 1, wc = w & 1;
    const int q = lane >> 4, r15 = lane & 15;

    // staging decode: A = 16 wave-rounds, B = 8; per wave: 4 A + 2 B calls
    int aRow[4], aOff[4], aR_[4], bRow[2], bOff[2], bR_[2];
    #pragma unroll
    for (int t = 0; t < 4; ++t) {
        int r = w + 4 * t, ch = r * 64 + lane;
        aR_[t] = r; aRow[t] = ch >> 3;
        aOff[t] = ((ch & 7) ^ ((ch >> 3) & 7)) * 8;
    }
    #pragma unroll
    for (int t = 0; t < 2; ++t) {
        int r = w + 4 * t, ch = r * 64 + lane;
        bR_[t] = r; bRow[t] = ch >> 3;
        bOff[t] = ((ch & 7) ^ ((ch >> 3) & 7)) * 8;
    }

#define STAGE(buf, k0)                                                            \
    {                                                                             \
        _Pragma("unroll")                                                         \
        for (int t = 0; t < 4; ++t)                                               \
            GLOAD16(Ap + (size_t)(c0 + aRow[t]) * S + (k0) + aOff[t],             \
                    &As[buf][aR_[t] * 512]);                                      \
        _Pragma("unroll")                                                         \
        for (int t = 0; t < 2; ++t)                                               \
            GLOAD16(Bp + (size_t)(n0 + bRow[t]) * S + (k0) + bOff[t],             \
                    &Bs[buf][bR_[t] * 512]);                                      \
    }

    f32x4 acc[4][2] = {};

    STAGE(0, 0);
    __syncthreads();

    const int sw0 = (q ^ (r15 & 7)) * 8;
    const int sw1 = ((4 + q) ^ (r15 & 7)) * 8;

    #pragma unroll 2
    for (int kt = 0; kt < S / 64; ++kt) {
        const int cur = kt & 1;
        // issue next K-tile DMA; lands during MFMA, drained by the barrier
        if (kt < S / 64 - 1) STAGE(cur ^ 1, (kt + 1) * 64);

        #pragma unroll
        for (int kk = 0; kk < 2; ++kk) {
            const int sz = kk ? sw1 : sw0;
            s16x8 af[4], bf[2];
            #pragma unroll
            for (int i = 0; i < 4; ++i)
                af[i] = *(const s16x8*)&As[cur][(wr * 64 + i * 16 + r15) * 64 + sz];
            #pragma unroll
            for (int j = 0; j < 2; ++j)
                bf[j] = *(const s16x8*)&Bs[cur][(wc * 32 + j * 16 + r15) * 64 + sz];
            #pragma unroll
            for (int i = 0; i < 4; ++i)
                #pragma unroll
                for (int j = 0; j < 2; ++j)
                    acc[i][j] = __builtin_amdgcn_mfma_f32_16x16x32_bf16(af[i], bf[j], acc[i][j], 0, 0, 0);
        }
        __syncthreads();  // drains vmcnt (next buf ready) + lgkm (reads done)
    }
#undef STAGE

    // epilogue: out = acc / L[n] + a (residual from L2-hot a16)
    float rcpL[2];
    #pragma unroll
    for (int j = 0; j < 2; ++j) {
        int n = n0 + wc * 32 + j * 16 + r15;
        float s = 0.f;
        #pragma unroll
        for (int mt = 0; mt < NMT; ++mt)
            s += Lp[(size_t)lb * NMT * S + (size_t)mt * S + n];
        rcpL[j] = 1.0f / s;
    }
    #pragma unroll
    for (int i = 0; i < 4; ++i) {
        #pragma unroll
        for (int rr = 0; rr < 4; ++rr) {
            int cc = c0 + wr * 64 + i * 16 + q * 4 + rr;
            size_t base = (size_t)cc * S;
            #pragma unroll
            for (int j = 0; j < 2; ++j) {
                int n = n0 + wc * 32 + j * 16 + r15;
                op[base + n] = acc[i][j][rr] * rcpL[j] + bf2f(Ap[base + n]);
            }
        }
    }
}

// ---- launch ----------------------------------------------------------------
extern "C" void kernel_launch(void* const* d_in, const int* in_sizes, int n_in,
                              void* d_out, int out_size, void* d_ws, size_t ws_size,
                              hipStream_t stream) {
    const float* a = (const float*)d_in[0];
    const float* b = (const float*)d_in[1];
    const float* c = (const float*)d_in[2];
    float* out = (float*)d_out;

    const size_t a16_bytes = (size_t)NBATCH * CDIM * S * 2;    // 8 MB
    const size_t bc_bytes = (size_t)NBATCH * S * DHEAD * 2;    // 2 MB each
    const size_t head = a16_bytes + 2 * bc_bytes;              // 12 MB
    const size_t perb = (size_t)S * S * 2 + (size_t)NMT * S * 4;
    int G = 1;
    if (ws_size > head + perb) {
        size_t g = (ws_size - head) / perb;
        G = (g >= NBATCH) ? NBATCH : (int)g;
        if (G < 1) G = 1;
    }
    unsigned short* a16 = (unsigned short*)d_ws;
    unsigned short* b16 = (unsigned short*)((char*)d_ws + a16_bytes);
    unsigned short* c16 = (unsigned short*)((char*)d_ws + a16_bytes + bc_bytes);
    unsigned short* E = (unsigned short*)((char*)d_ws + head);
    float* Lp = (float*)((char*)d_ws + head + (size_t)G * S * S * 2);

    cvt_kernel<<<1024, 256, 0, stream>>>(a, b, c, a16, b16, c16);

    const size_t lds1 = 34816 + 2 * 128 * 4;   // 35840 B
    for (int b0 = 0; b0 < NBATCH; b0 += G) {
        int nb = (NBATCH - b0 < G) ? (NBATCH - b0) : G;
        scores_kernel<<<NMT * 16 * nb, 256, lds1, stream>>>(b16, c16, E, Lp, b0, nb);
        gemm_kernel<<<64 * nb, 256, 0, stream>>>(a16, E, Lp, out, b0, nb);
    }
}

// Round 10
// 50.621 us; speedup vs baseline: 2.1492x; 1.2157x over previous
//
#include <hip/hip_runtime.h>
#include <stdint.h>

#define S 2048
#define DHEAD 64
#define CDIM 256
#define NBATCH 8
#define NMT 16   // S/128 m-tiles
#define NSTEP 32 // S/64 K-steps in gemm

typedef __attribute__((ext_vector_type(4))) float f32x4;
typedef __attribute__((ext_vector_type(8))) short s16x8;
typedef __attribute__((ext_vector_type(8))) _Float16 f16x8;
typedef __attribute__((ext_vector_type(4))) unsigned short u16x4;

static __device__ __forceinline__ unsigned short f2bf(float f) {
    unsigned int u = __builtin_bit_cast(unsigned int, f);
    unsigned int r = (u + 0x7FFFu + ((u >> 16) & 1u)) >> 16;  // RNE
    return (unsigned short)r;
}
static __device__ __forceinline__ unsigned short f2h(float f) {
    _Float16 h = (_Float16)f;
    return __builtin_bit_cast(unsigned short, h);
}
static __device__ __forceinline__ float bf2f(unsigned short u) {
    return __builtin_bit_cast(float, (unsigned int)u << 16);
}

// async global->LDS, 16B per lane; LDS dest = wave-uniform base + lane*16
#define GLOAD16(g, l)                                                              \
    __builtin_amdgcn_global_load_lds(                                              \
        (const __attribute__((address_space(1))) void*)(g),                        \
        (__attribute__((address_space(3))) void*)(l), 16, 0, 0)

// ---- kernel 0: a->bf16, b->f16, c->f16 -------------------------------------
__global__ __launch_bounds__(256) void cvt_kernel(
    const float* __restrict__ a, const float* __restrict__ b, const float* __restrict__ c,
    unsigned short* __restrict__ a16, unsigned short* __restrict__ b16,
    unsigned short* __restrict__ c16)
{
    const int na4 = NBATCH * CDIM * S / 4;
    const int nbc4 = NBATCH * S * DHEAD / 4;
    int i0 = blockIdx.x * 256 + threadIdx.x;
    int stride = gridDim.x * 256;
    for (int i = i0; i < na4; i += stride) {
        f32x4 v = ((const f32x4*)a)[i];
        u16x4 o; o.x = f2bf(v.x); o.y = f2bf(v.y); o.z = f2bf(v.z); o.w = f2bf(v.w);
        ((u16x4*)a16)[i] = o;
    }
    for (int i = i0; i < nbc4; i += stride) {
        f32x4 v = ((const f32x4*)b)[i];
        u16x4 o; o.x = f2h(v.x); o.y = f2h(v.y); o.z = f2h(v.z); o.w = f2h(v.w);
        ((u16x4*)b16)[i] = o;
        f32x4 u = ((const f32x4*)c)[i];
        u16x4 p; p.x = f2h(u.x); p.y = f2h(u.y); p.z = f2h(u.z); p.w = f2h(u.w);
        ((u16x4*)c16)[i] = p;
    }
}

// ---- kernel 1: E = exp(b @ c^T) via f16 MFMA (R9-verified, unchanged) ------
__global__ __launch_bounds__(256) void scores_kernel(
    const unsigned short* __restrict__ B16, const unsigned short* __restrict__ C16,
    unsigned short* __restrict__ E, float* __restrict__ Lp, int b0, int nb)
{
    const int bid = blockIdx.x;
    int lb, idx;
    if (nb == 8) { lb = bid & 7; idx = bid >> 3; }
    else { lb = bid / (NMT * 16); idx = bid - lb * (NMT * 16); }
    const int gb = b0 + lb;
    const int mt = idx & 15;
    const int m0 = mt * 128;
    const int n0 = (idx >> 4) * 128;
    const unsigned short* __restrict__ bp = B16 + (size_t)gb * S * DHEAD;
    const unsigned short* __restrict__ cp = C16 + (size_t)gb * S * DHEAD;
    unsigned short* __restrict__ Ep = E + (size_t)lb * S * S;

    extern __shared__ char smem[];
    unsigned short* cs = (unsigned short*)smem;          // [128][64] f16 swz
    unsigned short* bs = cs + 128 * 64;                  // [128][64] f16 swz
    unsigned short* es = (unsigned short*)smem;          // [128][136] bf16, alias
    float* Lsh = (float*)(smem + 34816);                 // [2][128]

    const int tid = threadIdx.x;
    const int lane = tid & 63;
    const int w = tid >> 6;
    const int wr = w >> 1, wc = w & 1;
    const int q = lane >> 4, r15 = lane & 15;

    #pragma unroll
    for (int t = 0; t < 4; ++t) {
        int r = w + 4 * t;
        int ch = r * 64 + lane;
        int row = ch >> 3;
        int off = ((ch & 7) ^ (row & 7)) * 8;  // shorts
        GLOAD16(cp + (size_t)(m0 + row) * DHEAD + off, &cs[r * 512]);
        GLOAD16(bp + (size_t)(n0 + row) * DHEAD + off, &bs[r * 512]);
    }
    __syncthreads();  // vmcnt(0) drain -> DMA complete

    f32x4 acc[4][4] = {};
    #pragma unroll
    for (int kk = 0; kk < 2; ++kk) {
        const int sz = ((kk * 4 + q) ^ (r15 & 7)) * 8;
        f16x8 af[4], bf[4];
        #pragma unroll
        for (int i = 0; i < 4; ++i)
            af[i] = *(const f16x8*)&cs[(wr * 64 + i * 16 + r15) * 64 + sz];
        #pragma unroll
        for (int j = 0; j < 4; ++j)
            bf[j] = *(const f16x8*)&bs[(wc * 64 + j * 16 + r15) * 64 + sz];
        #pragma unroll
        for (int i = 0; i < 4; ++i)
            #pragma unroll
            for (int j = 0; j < 4; ++j)
                acc[i][j] = __builtin_amdgcn_mfma_f32_16x16x32_f16(af[i], bf[j], acc[i][j], 0, 0, 0);
    }

    u16x4 pk[4][4];
    float sj[4] = {0.f, 0.f, 0.f, 0.f};
    #pragma unroll
    for (int i = 0; i < 4; ++i) {
        #pragma unroll
        for (int j = 0; j < 4; ++j) {
            float e0 = __expf(acc[i][j][0]);
            float e1 = __expf(acc[i][j][1]);
            float e2 = __expf(acc[i][j][2]);
            float e3 = __expf(acc[i][j][3]);
            pk[i][j].x = f2bf(e0); pk[i][j].y = f2bf(e1);
            pk[i][j].z = f2bf(e2); pk[i][j].w = f2bf(e3);
            sj[j] += (e0 + e1) + (e2 + e3);
        }
    }
    #pragma unroll
    for (int j = 0; j < 4; ++j) {
        sj[j] += __shfl_xor(sj[j], 16);
        sj[j] += __shfl_xor(sj[j], 32);
    }

    __syncthreads();  // all fragment reads retired -> es may overwrite cs/bs

    #pragma unroll
    for (int i = 0; i < 4; ++i)
        #pragma unroll
        for (int j = 0; j < 4; ++j) {
            int nl = wc * 64 + j * 16 + r15;
            int ml = wr * 64 + i * 16 + q * 4;
            *(u16x4*)&es[nl * 136 + ml] = pk[i][j];
        }
    if (q == 0) {
        #pragma unroll
        for (int j = 0; j < 4; ++j)
            Lsh[wr * 128 + wc * 64 + j * 16 + r15] = sj[j];
    }
    __syncthreads();

    if (tid < 128)
        Lp[(size_t)lb * NMT * S + (size_t)mt * S + n0 + tid] = Lsh[tid] + Lsh[128 + tid];

    #pragma unroll
    for (int t = 0; t < 8; ++t) {
        int ch = tid + 256 * t;
        int row = ch >> 4, off = ch & 15;
        f32x4 v = *(const f32x4*)&es[row * 136 + off * 8];
        *(f32x4*)&Ep[(size_t)(n0 + row) * S + m0 + off * 8] = v;
    }
}

// staging decode shared by both gemm variants
#define GEMM_DECODE()                                                             \
    const int tid = threadIdx.x;                                                  \
    const int lane = tid & 63;                                                    \
    const int w = tid >> 6;                                                       \
    const int wr = w >> 1, wc = w & 1;                                            \
    const int q = lane >> 4, r15 = lane & 15;                                     \
    int aRow[4], aOff[4], aR_[4], bRow[2], bOff[2], bR_[2];                       \
    _Pragma("unroll")                                                             \
    for (int t = 0; t < 4; ++t) {                                                 \
        int r = w + 4 * t, ch = r * 64 + lane;                                    \
        aR_[t] = r; aRow[t] = ch >> 3;                                            \
        aOff[t] = ((ch & 7) ^ ((ch >> 3) & 7)) * 8;                               \
    }                                                                             \
    _Pragma("unroll")                                                             \
    for (int t = 0; t < 2; ++t) {                                                 \
        int r = w + 4 * t, ch = r * 64 + lane;                                    \
        bR_[t] = r; bRow[t] = ch >> 3;                                            \
        bOff[t] = ((ch & 7) ^ ((ch >> 3) & 7)) * 8;                               \
    }

#define STAGEP(bufA, bufB, k0)                                                    \
    {                                                                             \
        _Pragma("unroll")                                                         \
        for (int t = 0; t < 4; ++t)                                               \
            GLOAD16(Ap + (size_t)(c0 + aRow[t]) * S + (k0) + aOff[t],             \
                    (bufA) + aR_[t] * 512);                                       \
        _Pragma("unroll")                                                         \
        for (int t = 0; t < 2; ++t)                                               \
            GLOAD16(Bp + (size_t)(n0 + bRow[t]) * S + (k0) + bOff[t],             \
                    (bufB) + bR_[t] * 512);                                       \
    }

#define GEMM_EPILOGUE()                                                           \
    float rcpL[2];                                                                \
    _Pragma("unroll")                                                             \
    for (int j = 0; j < 2; ++j) {                                                 \
        int n = n0 + wc * 32 + j * 16 + r15;                                      \
        float s = 0.f;                                                            \
        _Pragma("unroll")                                                         \
        for (int mt = 0; mt < NMT; ++mt)                                          \
            s += Lp[(size_t)lb * NMT * S + (size_t)mt * S + n];                   \
        rcpL[j] = 1.0f / s;                                                       \
    }                                                                             \
    _Pragma("unroll")                                                             \
    for (int i = 0; i < 4; ++i) {                                                 \
        _Pragma("unroll")                                                         \
        for (int rr = 0; rr < 4; ++rr) {                                          \
            int cc = c0 + wr * 64 + i * 16 + q * 4 + rr;                          \
            size_t base = (size_t)cc * S;                                         \
            _Pragma("unroll")                                                     \
            for (int j = 0; j < 2; ++j) {                                         \
                int n = n0 + wc * 32 + j * 16 + r15;                              \
                op[base + n] = acc[i][j][rr] * rcpL[j] + bf2f(Ap[base + n]);      \
            }                                                                     \
        }                                                                         \
    }

// ---- kernel 2 (primary): 3-buffer, counted-vmcnt, raw barriers (T3/T4/T5) --
// 128c x 64n, BK=64, 4 waves. Prefetch distance 2: steady-state vmcnt(12)
// (2 tiles x 6 loads/thread in flight) -- never drained to 0 in the loop.
__global__ __launch_bounds__(256, 2) void gemm_kernel3(
    const unsigned short* __restrict__ a16, const unsigned short* __restrict__ E,
    const float* __restrict__ Lp, float* __restrict__ out, int b0, int nb)
{
    const int bid = blockIdx.x;
    int lb, idx;
    if (nb == 8) { lb = bid & 7; idx = bid >> 3; }
    else { lb = bid / 64; idx = bid - lb * 64; }
    const int gb = b0 + lb;
    const int nt = idx >> 1, ct = idx & 1;
    const int n0 = nt * 64, c0 = ct * 128;

    const unsigned short* __restrict__ Ap = a16 + (size_t)gb * CDIM * S;
    const unsigned short* __restrict__ Bp = E + (size_t)lb * S * S;
    float* __restrict__ op = out + (size_t)gb * CDIM * S;

    extern __shared__ char gsm[];
    unsigned short* As[3];
    unsigned short* Bs[3];
    #pragma unroll
    for (int u = 0; u < 3; ++u) {
        As[u] = (unsigned short*)gsm + u * (128 * 64 + 64 * 64);
        Bs[u] = As[u] + 128 * 64;
    }

    GEMM_DECODE();

    f32x4 acc[4][2] = {};

    // prologue: tiles 0 and 1 in flight (12 outstanding loads/thread)
    STAGEP(As[0], Bs[0], 0);
    STAGEP(As[1], Bs[1], 64);

    const int sw0 = (q ^ (r15 & 7)) * 8;
    const int sw1 = ((4 + q) ^ (r15 & 7)) * 8;

    #pragma unroll
    for (int kt = 0; kt < NSTEP; ++kt) {
        const int cur = kt % 3;
        if (kt <= NSTEP - 3) {
            STAGEP(As[(kt + 2) % 3], Bs[(kt + 2) % 3], (kt + 2) * 64);
            asm volatile("s_waitcnt vmcnt(12)" ::: "memory");
        } else if (kt == NSTEP - 2) {
            asm volatile("s_waitcnt vmcnt(6)" ::: "memory");
        } else {
            asm volatile("s_waitcnt vmcnt(0)" ::: "memory");
        }
        __builtin_amdgcn_sched_barrier(0);
        __builtin_amdgcn_s_barrier();      // buf[cur] ready for all waves
        __builtin_amdgcn_sched_barrier(0);

        const unsigned short* Ar = As[cur];
        const unsigned short* Br = Bs[cur];
        #pragma unroll
        for (int kk = 0; kk < 2; ++kk) {
            const int sz = kk ? sw1 : sw0;
            s16x8 af[4], bf[2];
            #pragma unroll
            for (int i = 0; i < 4; ++i)
                af[i] = *(const s16x8*)&Ar[(wr * 64 + i * 16 + r15) * 64 + sz];
            #pragma unroll
            for (int j = 0; j < 2; ++j)
                bf[j] = *(const s16x8*)&Br[(wc * 32 + j * 16 + r15) * 64 + sz];
            __builtin_amdgcn_s_setprio(1);
            #pragma unroll
            for (int i = 0; i < 4; ++i)
                #pragma unroll
                for (int j = 0; j < 2; ++j)
                    acc[i][j] = __builtin_amdgcn_mfma_f32_16x16x32_bf16(af[i], bf[j], acc[i][j], 0, 0, 0);
            __builtin_amdgcn_s_setprio(0);
        }

        __builtin_amdgcn_sched_barrier(0);
        __builtin_amdgcn_s_barrier();      // reads of buf[cur] retired (lgkm
                                           // drained by MFMA deps) before the
                                           // next iter's STAGE overwrites it
    }

    GEMM_EPILOGUE();
}

// ---- kernel 2 (fallback): R9 2-buffer __syncthreads version ----------------
__global__ __launch_bounds__(256, 2) void gemm_kernel2(
    const unsigned short* __restrict__ a16, const unsigned short* __restrict__ E,
    const float* __restrict__ Lp, float* __restrict__ out, int b0, int nb)
{
    const int bid = blockIdx.x;
    int lb, idx;
    if (nb == 8) { lb = bid & 7; idx = bid >> 3; }
    else { lb = bid / 64; idx = bid - lb * 64; }
    const int gb = b0 + lb;
    const int nt = idx >> 1, ct = idx & 1;
    const int n0 = nt * 64, c0 = ct * 128;

    const unsigned short* __restrict__ Ap = a16 + (size_t)gb * CDIM * S;
    const unsigned short* __restrict__ Bp = E + (size_t)lb * S * S;
    float* __restrict__ op = out + (size_t)gb * CDIM * S;

    __shared__ unsigned short AsS[2][128 * 64];
    __shared__ unsigned short BsS[2][64 * 64];

    GEMM_DECODE();

    f32x4 acc[4][2] = {};

    STAGEP(AsS[0], BsS[0], 0);
    __syncthreads();

    const int sw0 = (q ^ (r15 & 7)) * 8;
    const int sw1 = ((4 + q) ^ (r15 & 7)) * 8;

    #pragma unroll 2
    for (int kt = 0; kt < NSTEP; ++kt) {
        const int cur = kt & 1;
        if (kt < NSTEP - 1) STAGEP(AsS[cur ^ 1], BsS[cur ^ 1], (kt + 1) * 64);

        #pragma unroll
        for (int kk = 0; kk < 2; ++kk) {
            const int sz = kk ? sw1 : sw0;
            s16x8 af[4], bf[2];
            #pragma unroll
            for (int i = 0; i < 4; ++i)
                af[i] = *(const s16x8*)&AsS[cur][(wr * 64 + i * 16 + r15) * 64 + sz];
            #pragma unroll
            for (int j = 0; j < 2; ++j)
                bf[j] = *(const s16x8*)&BsS[cur][(wc * 32 + j * 16 + r15) * 64 + sz];
            #pragma unroll
            for (int i = 0; i < 4; ++i)
                #pragma unroll
                for (int j = 0; j < 2; ++j)
                    acc[i][j] = __builtin_amdgcn_mfma_f32_16x16x32_bf16(af[i], bf[j], acc[i][j], 0, 0, 0);
        }
        __syncthreads();
    }

    GEMM_EPILOGUE();
}

// ---- launch ----------------------------------------------------------------
extern "C" void kernel_launch(void* const* d_in, const int* in_sizes, int n_in,
                              void* d_out, int out_size, void* d_ws, size_t ws_size,
                              hipStream_t stream) {
    const float* a = (const float*)d_in[0];
    const float* b = (const float*)d_in[1];
    const float* c = (const float*)d_in[2];
    float* out = (float*)d_out;

    const size_t a16_bytes = (size_t)NBATCH * CDIM * S * 2;    // 8 MB
    const size_t bc_bytes = (size_t)NBATCH * S * DHEAD * 2;    // 2 MB each
    const size_t head = a16_bytes + 2 * bc_bytes;              // 12 MB
    const size_t perb = (size_t)S * S * 2 + (size_t)NMT * S * 4;
    int G = 1;
    if (ws_size > head + perb) {
        size_t g = (ws_size - head) / perb;
        G = (g >= NBATCH) ? NBATCH : (int)g;
        if (G < 1) G = 1;
    }
    unsigned short* a16 = (unsigned short*)d_ws;
    unsigned short* b16 = (unsigned short*)((char*)d_ws + a16_bytes);
    unsigned short* c16 = (unsigned short*)((char*)d_ws + a16_bytes + bc_bytes);
    unsigned short* E = (unsigned short*)((char*)d_ws + head);
    float* Lp = (float*)((char*)d_ws + head + (size_t)G * S * S * 2);

    const int gemm_lds3 = 3 * (128 * 64 + 64 * 64) * 2;  // 73728 B
    hipError_t attr_ok = hipFuncSetAttribute(
        reinterpret_cast<const void*>(gemm_kernel3),
        hipFuncAttributeMaxDynamicSharedMemorySize, gemm_lds3);

    cvt_kernel<<<1024, 256, 0, stream>>>(a, b, c, a16, b16, c16);

    const size_t lds1 = 34816 + 2 * 128 * 4;   // 35840 B
    for (int b0 = 0; b0 < NBATCH; b0 += G) {
        int nb = (NBATCH - b0 < G) ? (NBATCH - b0) : G;
        scores_kernel<<<NMT * 16 * nb, 256, lds1, stream>>>(b16, c16, E, Lp, b0, nb);
        if (attr_ok == hipSuccess)
            gemm_kernel3<<<64 * nb, 256, gemm_lds3, stream>>>(a16, E, Lp, out, b0, nb);
        else
            gemm_kernel2<<<64 * nb, 256, 0, stream>>>(a16, E, Lp, out, b0, nb);
    }
}